// Round 4
// baseline (450.188 us; speedup 1.0000x reference)
//
#include <hip/hip_runtime.h>

// GCN 2-layer: out = A(relu(A x W1 + b1) W2) + b2, A = sym-normalized adj + self-loops.
// R4: dense radix-partition by dst bucket (128 nodes/bucket) -> zero per-edge global
// atomics (R3's k_hist_rank was 147us: 3.2M fabric RMW @ ~22G/s). Aggregation happens
// in LDS tiles (ds_add_f32), degree/histograms in LDS, partition offsets via dense scans.

#define B 256
#define NB_MAX 1024
#define BDIV 128          // nodes per bucket (pow2 -> shift/mask)
#define BSHIFT 7
#define CHUNK 8192        // edges per partition block

// ---------------- partition: per-block LDS histogram (dense flush) ----------------
__global__ __launch_bounds__(256) void k_phist(const int* __restrict__ dst,
                                               int* __restrict__ hists,
                                               int E, int NB, int NBLK) {
    __shared__ int h[NB_MAX];
    int tid = threadIdx.x, blk = blockIdx.x;
    for (int b = tid; b < NB; b += 256) h[b] = 0;
    __syncthreads();
    int start = blk * CHUNK;
    int end = min(start + CHUNK, E);
    for (int e = start + tid; e < end; e += 256)
        atomicAdd(&h[((unsigned)dst[e]) >> BSHIFT], 1);
    __syncthreads();
    for (int b = tid; b < NB; b += 256) hists[b * NBLK + blk] = h[b];
}

// per-bucket exclusive scan over NBLK block-counts (NBLK <= 512)
__global__ __launch_bounds__(512) void k_pscan1(int* __restrict__ hists,
                                                int* __restrict__ totals, int NBLK) {
    __shared__ int s[512];
    int b = blockIdx.x, tid = threadIdx.x;
    int v = (tid < NBLK) ? hists[b * NBLK + tid] : 0;
    s[tid] = v;
    __syncthreads();
    for (int off = 1; off < 512; off <<= 1) {
        int u = (tid >= off) ? s[tid - off] : 0;
        __syncthreads();
        s[tid] += u;
        __syncthreads();
    }
    if (tid < NBLK) hists[b * NBLK + tid] = s[tid] - v;  // exclusive within bucket
    if (tid == 511) totals[b] = s[511];
}

// scan bucket totals -> bucket bases (NB <= 1024); base[NB] = E
__global__ __launch_bounds__(1024) void k_pscan2(const int* __restrict__ totals,
                                                 int* __restrict__ base, int NB) {
    __shared__ int s[1024];
    int tid = threadIdx.x;
    int v = (tid < NB) ? totals[tid] : 0;
    s[tid] = v;
    __syncthreads();
    for (int off = 1; off < 1024; off <<= 1) {
        int u = (tid >= off) ? s[tid - off] : 0;
        __syncthreads();
        s[tid] += u;
        __syncthreads();
    }
    if (tid < NB) base[tid] = s[tid] - v;
    if (tid == 1023) base[NB] = s[1023];
}

// move edges into bucket regions; payload = src | local_dst<<20 (no global atomics)
__global__ __launch_bounds__(256) void k_move(const int* __restrict__ src,
                                              const int* __restrict__ dst,
                                              const int* __restrict__ hists,
                                              const int* __restrict__ base,
                                              unsigned* __restrict__ packed,
                                              int E, int NB, int NBLK) {
    __shared__ int cnt[NB_MAX];
    int tid = threadIdx.x, blk = blockIdx.x;
    for (int b = tid; b < NB; b += 256) cnt[b] = base[b] + hists[b * NBLK + blk];
    __syncthreads();
    int start = blk * CHUNK;
    int end = min(start + CHUNK, E);
    for (int e = start + tid; e < end; e += 256) {
        unsigned d = (unsigned)dst[e];
        int b = d >> BSHIFT;
        int r = atomicAdd(&cnt[b], 1);
        packed[r] = (unsigned)src[e] | ((d & (BDIV - 1u)) << 20);
    }
}

// per-bucket degree -> dinv = rsqrt(deg+1)
__global__ __launch_bounds__(256) void k_deg(const unsigned* __restrict__ packed,
                                             const int* __restrict__ base,
                                             float* __restrict__ dinv, int n) {
    __shared__ int h[BDIV];
    int b = blockIdx.x, tid = threadIdx.x;
    if (tid < BDIV) h[tid] = 0;
    __syncthreads();
    int s0 = base[b], s1 = base[b + 1];
    for (int i = s0 + tid; i < s1; i += 256)
        atomicAdd(&h[packed[i] >> 20], 1);
    __syncthreads();
    if (tid < BDIV) {
        int node = b * BDIV + tid;
        if (node < n) dinv[node] = rsqrtf((float)(h[tid] + 1));
    }
}

// layer-1: LDS-tile aggregation in input space (16f) + fused MLP -> t[2 per node]
__global__ __launch_bounds__(256) void k_l1agg(const float* __restrict__ x,
                                               const unsigned* __restrict__ packed,
                                               const int* __restrict__ base,
                                               const float* __restrict__ dinv,
                                               const float* __restrict__ W1,
                                               const float* __restrict__ b1,
                                               const float* __restrict__ W2,
                                               float* __restrict__ t, int n) {
    __shared__ float tile[BDIV * 17];  // stride 17: break 32-bank power-of-2 conflicts
    __shared__ float ldinv[BDIV];
    __shared__ float sW1[512], sb1[32], sW2[64];
    int b = blockIdx.x, tid = threadIdx.x;
    for (int k = tid; k < BDIV * 17; k += 256) tile[k] = 0.f;
    for (int k = tid; k < 512; k += 256) sW1[k] = W1[k];
    if (tid < 64) sW2[tid] = W2[tid];
    if (tid < 32) sb1[tid] = b1[tid];
    if (tid < BDIV) {
        int node = b * BDIV + tid;
        ldinv[tid] = (node < n) ? dinv[node] : 0.f;
    }
    __syncthreads();
    int s0 = base[b], s1 = base[b + 1];
    for (int i = s0 + tid; i < s1; i += 256) {
        unsigned u = packed[i];
        int s = (int)(u & 0xFFFFFu);
        int l = (int)(u >> 20);
        float w = dinv[s] * ldinv[l];
        const float4* xv = (const float4*)(x + (size_t)s * 16);
        float* tp = tile + l * 17;
#pragma unroll
        for (int q = 0; q < 4; ++q) {
            float4 v = xv[q];
            atomicAdd(tp + 4 * q + 0, v.x * w);
            atomicAdd(tp + 4 * q + 1, v.y * w);
            atomicAdd(tp + 4 * q + 2, v.z * w);
            atomicAdd(tp + 4 * q + 3, v.w * w);
        }
    }
    __syncthreads();
    int node = b * BDIV + tid;
    if (tid < BDIV && node < n) {
        float wself = ldinv[tid] * ldinv[tid];
        const float4* xv = (const float4*)(x + (size_t)node * 16);
        float agg[16];
#pragma unroll
        for (int q = 0; q < 4; ++q) {
            float4 v = xv[q];
            agg[4 * q + 0] = tile[tid * 17 + 4 * q + 0] + v.x * wself;
            agg[4 * q + 1] = tile[tid * 17 + 4 * q + 1] + v.y * wself;
            agg[4 * q + 2] = tile[tid * 17 + 4 * q + 2] + v.z * wself;
            agg[4 * q + 3] = tile[tid * 17 + 4 * q + 3] + v.w * wself;
        }
        float t0 = 0.f, t1 = 0.f;
#pragma unroll
        for (int j = 0; j < 32; ++j) {
            float acc = sb1[j];
#pragma unroll
            for (int k = 0; k < 16; ++k) acc = fmaf(agg[k], sW1[k * 32 + j], acc);
            float h = fmaxf(acc, 0.f);
            t0 = fmaf(h, sW2[j * 2 + 0], t0);
            t1 = fmaf(h, sW2[j * 2 + 1], t1);
        }
        *(float2*)(t + (size_t)node * 2) = make_float2(t0, t1);
    }
}

// layer-2: LDS-tile aggregation in output space (2f) -> out
__global__ __launch_bounds__(256) void k_l2agg(const float* __restrict__ t,
                                               const unsigned* __restrict__ packed,
                                               const int* __restrict__ base,
                                               const float* __restrict__ dinv,
                                               const float* __restrict__ b2,
                                               float* __restrict__ out, int n) {
    __shared__ float tile[BDIV * 3];
    __shared__ float ldinv[BDIV];
    int b = blockIdx.x, tid = threadIdx.x;
    for (int k = tid; k < BDIV * 3; k += 256) tile[k] = 0.f;
    if (tid < BDIV) {
        int node = b * BDIV + tid;
        ldinv[tid] = (node < n) ? dinv[node] : 0.f;
    }
    __syncthreads();
    int s0 = base[b], s1 = base[b + 1];
    for (int i = s0 + tid; i < s1; i += 256) {
        unsigned u = packed[i];
        int s = (int)(u & 0xFFFFFu);
        int l = (int)(u >> 20);
        float w = dinv[s] * ldinv[l];
        float2 tv = *(const float2*)(t + (size_t)s * 2);
        atomicAdd(&tile[l * 3 + 0], tv.x * w);
        atomicAdd(&tile[l * 3 + 1], tv.y * w);
    }
    __syncthreads();
    int node = b * BDIV + tid;
    if (tid < BDIV && node < n) {
        float wself = ldinv[tid] * ldinv[tid];
        float2 tv = *(const float2*)(t + (size_t)node * 2);
        out[(size_t)node * 2 + 0] = tile[tid * 3 + 0] + tv.x * wself + b2[0];
        out[(size_t)node * 2 + 1] = tile[tid * 3 + 1] + tv.y * wself + b2[1];
    }
}

// ---------------- R3 CSR fallback kernels ----------------

__global__ void k_zero(int* __restrict__ cnt, int n) {
    int i = blockIdx.x * blockDim.x + threadIdx.x;
    if (i < n) cnt[i] = 0;
}
__global__ void k_hist_rank(const int* __restrict__ dst, int* __restrict__ cnt,
                            int* __restrict__ rank, int E) {
    int e = blockIdx.x * blockDim.x + threadIdx.x;
    if (e < E) rank[e] = atomicAdd(&cnt[dst[e]], 1);
}
__global__ __launch_bounds__(256) void k_blocksum(const int* __restrict__ cnt,
                                                  int* __restrict__ bsum, int n) {
    __shared__ int s[256];
    int tid = threadIdx.x;
    int bse = blockIdx.x * 1024 + tid * 4;
    int sum = 0;
#pragma unroll
    for (int q = 0; q < 4; ++q) {
        int i = bse + q;
        if (i < n) sum += cnt[i];
    }
    s[tid] = sum;
    __syncthreads();
    for (int off = 128; off > 0; off >>= 1) {
        if (tid < off) s[tid] += s[tid + off];
        __syncthreads();
    }
    if (tid == 0) bsum[blockIdx.x] = s[0];
}
__global__ __launch_bounds__(1024) void k_scan_bsums(const int* __restrict__ bsum,
                                                     int* __restrict__ boff, int nb,
                                                     int* __restrict__ rowptr, int n, int E) {
    __shared__ int s[1024];
    int tid = threadIdx.x;
    int v = (tid < nb) ? bsum[tid] : 0;
    s[tid] = v;
    __syncthreads();
    for (int off = 1; off < 1024; off <<= 1) {
        int u = (tid >= off) ? s[tid - off] : 0;
        __syncthreads();
        s[tid] += u;
        __syncthreads();
    }
    if (tid < nb) boff[tid] = s[tid] - v;
    if (tid == 0) rowptr[n] = E;
}
__global__ __launch_bounds__(256) void k_scan_apply(const int* __restrict__ cnt,
                                                    const int* __restrict__ boff,
                                                    int* __restrict__ rowptr,
                                                    float* __restrict__ dinv, int n) {
    __shared__ int s[256];
    int tid = threadIdx.x;
    int bse = blockIdx.x * 1024 + tid * 4;
    int c[4];
    int sum = 0;
#pragma unroll
    for (int q = 0; q < 4; ++q) {
        int i = bse + q;
        c[q] = (i < n) ? cnt[i] : 0;
        sum += c[q];
    }
    s[tid] = sum;
    __syncthreads();
    for (int off = 1; off < 256; off <<= 1) {
        int u = (tid >= off) ? s[tid - off] : 0;
        __syncthreads();
        s[tid] += u;
        __syncthreads();
    }
    int run = boff[blockIdx.x] + s[tid] - sum;
#pragma unroll
    for (int q = 0; q < 4; ++q) {
        int i = bse + q;
        if (i < n) {
            rowptr[i] = run;
            run += c[q];
            dinv[i] = rsqrtf((float)(c[q] + 1));
        }
    }
}
__global__ void k_fill_rank(const int* __restrict__ src, const int* __restrict__ dst,
                            const int* __restrict__ rowptr, const int* __restrict__ rank,
                            int* __restrict__ col, int E) {
    int e = blockIdx.x * blockDim.x + threadIdx.x;
    if (e >= E) return;
    int d = dst[e];
    col[rowptr[d] + rank[e]] = src[e];
}
__global__ __launch_bounds__(256) void k_l1(const float* __restrict__ x,
                                            const int* __restrict__ rowptr,
                                            const int* __restrict__ col,
                                            const float* __restrict__ dinv,
                                            const float* __restrict__ W1,
                                            const float* __restrict__ b1,
                                            const float* __restrict__ W2,
                                            float* __restrict__ t, int n) {
    __shared__ float sW1[16 * 32];
    __shared__ float sW2[32 * 2];
    __shared__ float sb1[32];
    int tid = threadIdx.x;
    for (int k = tid; k < 512; k += 256) sW1[k] = W1[k];
    if (tid < 64) sW2[tid] = W2[tid];
    if (tid < 32) sb1[tid] = b1[tid];
    __syncthreads();
    int i = blockIdx.x * blockDim.x + tid;
    if (i >= n) return;
    float di = dinv[i];
    float w0 = di * di;
    float agg[16];
    const float4* xv = (const float4*)(x + (size_t)i * 16);
#pragma unroll
    for (int q = 0; q < 4; ++q) {
        float4 v = xv[q];
        agg[4 * q + 0] = v.x * w0; agg[4 * q + 1] = v.y * w0;
        agg[4 * q + 2] = v.z * w0; agg[4 * q + 3] = v.w * w0;
    }
    int beg = rowptr[i], fin = rowptr[i + 1];
    for (int j = beg; j < fin; ++j) {
        int s = col[j];
        float w = dinv[s] * di;
        const float4* sv = (const float4*)(x + (size_t)s * 16);
#pragma unroll
        for (int q = 0; q < 4; ++q) {
            float4 v = sv[q];
            agg[4 * q + 0] = fmaf(v.x, w, agg[4 * q + 0]);
            agg[4 * q + 1] = fmaf(v.y, w, agg[4 * q + 1]);
            agg[4 * q + 2] = fmaf(v.z, w, agg[4 * q + 2]);
            agg[4 * q + 3] = fmaf(v.w, w, agg[4 * q + 3]);
        }
    }
    float t0 = 0.f, t1 = 0.f;
#pragma unroll
    for (int j = 0; j < 32; ++j) {
        float acc = sb1[j];
#pragma unroll
        for (int k = 0; k < 16; ++k) acc = fmaf(agg[k], sW1[k * 32 + j], acc);
        float h = fmaxf(acc, 0.f);
        t0 = fmaf(h, sW2[j * 2 + 0], t0);
        t1 = fmaf(h, sW2[j * 2 + 1], t1);
    }
    t[(size_t)i * 2 + 0] = t0;
    t[(size_t)i * 2 + 1] = t1;
}
__global__ void k_l2(const int* __restrict__ rowptr, const int* __restrict__ col,
                     const float* __restrict__ dinv, const float* __restrict__ t,
                     const float* __restrict__ b2, float* __restrict__ out, int n) {
    int i = blockIdx.x * blockDim.x + threadIdx.x;
    if (i >= n) return;
    float di = dinv[i];
    float2 ts = *(const float2*)(t + (size_t)i * 2);
    float acc0 = ts.x * di * di, acc1 = ts.y * di * di;
    int beg = rowptr[i], fin = rowptr[i + 1];
    for (int j = beg; j < fin; ++j) {
        int s = col[j];
        float w = dinv[s] * di;
        float2 tv = *(const float2*)(t + (size_t)s * 2);
        acc0 = fmaf(tv.x, w, acc0);
        acc1 = fmaf(tv.y, w, acc1);
    }
    out[(size_t)i * 2 + 0] = acc0 + b2[0];
    out[(size_t)i * 2 + 1] = acc1 + b2[1];
}

static inline size_t align4(size_t v) { return (v + 3) & ~(size_t)3; }

extern "C" void kernel_launch(void* const* d_in, const int* in_sizes, int n_in,
                              void* d_out, int out_size, void* d_ws, size_t ws_size,
                              hipStream_t stream) {
    const float* x  = (const float*)d_in[0];
    const int*   ei = (const int*)d_in[1];
    const float* W1 = (const float*)d_in[2];
    const float* b1 = (const float*)d_in[3];
    const float* W2 = (const float*)d_in[4];
    const float* b2 = (const float*)d_in[5];
    float* out = (float*)d_out;

    const int n = in_sizes[0] / 16;
    const int E = in_sizes[1] / 2;
    const int* src = ei;
    const int* dst = ei + E;

    const int gn = (n + B - 1) / B;
    const int ge = (E + B - 1) / B;

    const int NB   = (n + BDIV - 1) / BDIV;      // buckets
    const int NBLK = (E + CHUNK - 1) / CHUNK;    // partition blocks

    // partition-path ws layout (4B units, 16B-aligned regions):
    // hists[NB*NBLK] | totals[NB] | base[NB+1] | dinv[n] | packed[E] | t[2n]
    size_t o_hists  = 0;
    size_t o_totals = align4(o_hists + (size_t)NB * NBLK);
    size_t o_base   = align4(o_totals + NB);
    size_t o_dinv   = align4(o_base + NB + 1);
    size_t o_packed = align4(o_dinv + n);
    size_t o_t      = align4(o_packed + E);
    size_t need_part = (o_t + (size_t)2 * n) * 4 + 64;

    bool part_ok = (n <= 131072) && (NB <= NB_MAX) && (NBLK <= 512) &&
                   (ws_size >= need_part);

    if (part_ok) {
        int* ws = (int*)d_ws;
        int*      hists  = ws + o_hists;
        int*      totals = ws + o_totals;
        int*      base   = ws + o_base;
        float*    dinv   = (float*)(ws + o_dinv);
        unsigned* packed = (unsigned*)(ws + o_packed);
        float*    t      = (float*)(ws + o_t);

        k_phist<<<NBLK, 256, 0, stream>>>(dst, hists, E, NB, NBLK);
        k_pscan1<<<NB, 512, 0, stream>>>(hists, totals, NBLK);
        k_pscan2<<<1, 1024, 0, stream>>>(totals, base, NB);
        k_move<<<NBLK, 256, 0, stream>>>(src, dst, hists, base, packed, E, NB, NBLK);
        k_deg<<<NB, 256, 0, stream>>>(packed, base, dinv, n);
        k_l1agg<<<NB, 256, 0, stream>>>(x, packed, base, dinv, W1, b1, W2, t, n);
        k_l2agg<<<NB, 256, 0, stream>>>(t, packed, base, dinv, b2, out, n);
        return;
    }

    // ---- R3 CSR fallback ----
    const int nb = (n + 1023) / 1024;
    size_t tmax = (size_t)(E > 2 * n ? E : 2 * n);
    size_t need_rank = ((size_t)(3 * n + 1 + 2 * nb) + E + tmax) * 4 + 64;
    if (ws_size >= need_rank && nb <= 1024) {
        int*   cnt    = (int*)d_ws;
        int*   rowptr = cnt + n;
        int*   col    = rowptr + (n + 1);
        float* dinv   = (float*)(col + E);
        int*   bsum   = (int*)(dinv + n);
        int*   boff   = bsum + nb;
        int*   rank   = boff + nb;
        float* t      = (float*)rank;

        k_zero<<<gn, B, 0, stream>>>(cnt, n);
        k_hist_rank<<<ge, B, 0, stream>>>(dst, cnt, rank, E);
        k_blocksum<<<nb, 256, 0, stream>>>(cnt, bsum, n);
        k_scan_bsums<<<1, 1024, 0, stream>>>(bsum, boff, nb, rowptr, n, E);
        k_scan_apply<<<nb, 256, 0, stream>>>(cnt, boff, rowptr, dinv, n);
        k_fill_rank<<<ge, B, 0, stream>>>(src, dst, rowptr, rank, col, E);
        k_l1<<<gn, B, 0, stream>>>(x, rowptr, col, dinv, W1, b1, W2, t, n);
        k_l2<<<gn, B, 0, stream>>>(rowptr, col, dinv, t, b2, out, n);
    }
}

// Round 5
// 214.088 us; speedup vs baseline: 2.1028x; 2.1028x over previous
//
#include <hip/hip_runtime.h>

// GCN 2-layer: out = A(relu(A x W1 + b1) W2) + b2, A = sym-normalized adj + self-loops.
// R5 hybrid: partition-based CSR build (zero global atomics; R4's machinery) feeding
// R3's node-parallel CSR gathers (zero atomics, good ILP). R4's edge-parallel LDS-tile
// aggregation (344us: latency-bound, 22% occ) is dropped; R3's k_hist_rank (147us of
// fabric RMW) is replaced by k_phist/k_move/k_bucket_csr.

#define B 256
#define NB_MAX 1024
#define BDIV 128          // nodes per bucket (pow2)
#define BSHIFT 7
#define CHUNK 8192        // edges per partition block

// ---------------- partition: per-block LDS histogram over buckets ----------------
__global__ __launch_bounds__(256) void k_phist(const int* __restrict__ dst,
                                               int* __restrict__ hists,
                                               int E, int NB, int NBLK) {
    __shared__ int h[NB_MAX];
    int tid = threadIdx.x, blk = blockIdx.x;
    for (int b = tid; b < NB; b += 256) h[b] = 0;
    __syncthreads();
    int start = blk * CHUNK;
    int end = min(start + CHUNK, E);
    for (int e = start + tid; e < end; e += 256)
        atomicAdd(&h[((unsigned)dst[e]) >> BSHIFT], 1);
    __syncthreads();
    for (int b = tid; b < NB; b += 256) hists[b * NBLK + blk] = h[b];
}

// per-bucket exclusive scan over NBLK block-counts (NBLK <= 512)
__global__ __launch_bounds__(512) void k_pscan1(int* __restrict__ hists,
                                                int* __restrict__ totals, int NBLK) {
    __shared__ int s[512];
    int b = blockIdx.x, tid = threadIdx.x;
    int v = (tid < NBLK) ? hists[b * NBLK + tid] : 0;
    s[tid] = v;
    __syncthreads();
    for (int off = 1; off < 512; off <<= 1) {
        int u = (tid >= off) ? s[tid - off] : 0;
        __syncthreads();
        s[tid] += u;
        __syncthreads();
    }
    if (tid < NBLK) hists[b * NBLK + tid] = s[tid] - v;  // exclusive within bucket
    if (tid == 511) totals[b] = s[511];
}

// scan bucket totals -> bucket bases (NB <= 1024); base[NB]=E; rowptr[n]=E
__global__ __launch_bounds__(1024) void k_pscan2(const int* __restrict__ totals,
                                                 int* __restrict__ base, int NB,
                                                 int* __restrict__ rowptr, int n, int E) {
    __shared__ int s[1024];
    int tid = threadIdx.x;
    int v = (tid < NB) ? totals[tid] : 0;
    s[tid] = v;
    __syncthreads();
    for (int off = 1; off < 1024; off <<= 1) {
        int u = (tid >= off) ? s[tid - off] : 0;
        __syncthreads();
        s[tid] += u;
        __syncthreads();
    }
    if (tid < NB) base[tid] = s[tid] - v;
    if (tid == 1023) { base[NB] = s[1023]; rowptr[n] = E; }
}

// move edges into bucket regions; payload = src | local_dst<<20 (no global atomics)
__global__ __launch_bounds__(256) void k_move(const int* __restrict__ src,
                                              const int* __restrict__ dst,
                                              const int* __restrict__ hists,
                                              const int* __restrict__ base,
                                              unsigned* __restrict__ packed,
                                              int E, int NB, int NBLK) {
    __shared__ int cnt[NB_MAX];
    int tid = threadIdx.x, blk = blockIdx.x;
    for (int b = tid; b < NB; b += 256) cnt[b] = base[b] + hists[b * NBLK + blk];
    __syncthreads();
    int start = blk * CHUNK;
    int end = min(start + CHUNK, E);
    for (int e = start + tid; e < end; e += 256) {
        unsigned d = (unsigned)dst[e];
        int b = d >> BSHIFT;
        int r = atomicAdd(&cnt[b], 1);
        packed[r] = (unsigned)src[e] | ((d & (BDIV - 1u)) << 20);
    }
}

// per-bucket: LDS hist over 128 local nodes -> scan -> rowptr/dinv + place col
__global__ __launch_bounds__(256) void k_bucket_csr(const unsigned* __restrict__ packed,
                                                    const int* __restrict__ base,
                                                    int* __restrict__ rowptr,
                                                    float* __restrict__ dinv,
                                                    int* __restrict__ col, int n) {
    __shared__ int lcnt[BDIV];
    __shared__ int lexc[BDIV];
    int b = blockIdx.x, tid = threadIdx.x;
    if (tid < BDIV) lcnt[tid] = 0;
    __syncthreads();
    int s0 = base[b], s1 = base[b + 1];
    for (int i = s0 + tid; i < s1; i += 256)
        atomicAdd(&lcnt[packed[i] >> 20], 1);
    __syncthreads();
    // Hillis-Steele inclusive scan over 128 counts (all threads hit barriers)
    int v = (tid < BDIV) ? lcnt[tid] : 0;
    if (tid < BDIV) lexc[tid] = v;
    __syncthreads();
    for (int off = 1; off < BDIV; off <<= 1) {
        int u = (tid < BDIV && tid >= off) ? lexc[tid - off] : 0;
        __syncthreads();
        if (tid < BDIV) lexc[tid] += u;
        __syncthreads();
    }
    if (tid < BDIV) {
        lexc[tid] -= v;  // exclusive
        int node = b * BDIV + tid;
        if (node < n) {
            rowptr[node] = s0 + lexc[tid];
            dinv[node] = rsqrtf((float)(v + 1));  // +1 self-loop
        }
        lcnt[tid] = 0;  // reuse as fill cursor
    }
    __syncthreads();
    for (int i = s0 + tid; i < s1; i += 256) {
        unsigned u = packed[i];
        int l = (int)(u >> 20);
        int pos = s0 + lexc[l] + atomicAdd(&lcnt[l], 1);
        col[pos] = (int)(u & 0xFFFFFu);
    }
}

// ---------------- layer 1 gather (input space, 16 feats) + fused MLP ----------------
__global__ __launch_bounds__(256) void k_l1(const float* __restrict__ x,
                                            const int* __restrict__ rowptr,
                                            const int* __restrict__ col,
                                            const float* __restrict__ dinv,
                                            const float* __restrict__ W1,
                                            const float* __restrict__ b1,
                                            const float* __restrict__ W2,
                                            float* __restrict__ t, int n) {
    __shared__ float sW1[16 * 32];
    __shared__ float sW2[32 * 2];
    __shared__ float sb1[32];
    int tid = threadIdx.x;
    for (int k = tid; k < 512; k += 256) sW1[k] = W1[k];
    if (tid < 64) sW2[tid] = W2[tid];
    if (tid < 32) sb1[tid] = b1[tid];
    __syncthreads();
    int i = blockIdx.x * blockDim.x + tid;
    if (i >= n) return;
    float di = dinv[i];
    float w0 = di * di;
    float agg[16];
    const float4* xv = (const float4*)(x + (size_t)i * 16);
#pragma unroll
    for (int q = 0; q < 4; ++q) {
        float4 v = xv[q];
        agg[4 * q + 0] = v.x * w0; agg[4 * q + 1] = v.y * w0;
        agg[4 * q + 2] = v.z * w0; agg[4 * q + 3] = v.w * w0;
    }
    int beg = rowptr[i], fin = rowptr[i + 1];
    for (int j = beg; j < fin; ++j) {
        int s = col[j];
        float w = dinv[s] * di;
        const float4* sv = (const float4*)(x + (size_t)s * 16);
#pragma unroll
        for (int q = 0; q < 4; ++q) {
            float4 v = sv[q];
            agg[4 * q + 0] = fmaf(v.x, w, agg[4 * q + 0]);
            agg[4 * q + 1] = fmaf(v.y, w, agg[4 * q + 1]);
            agg[4 * q + 2] = fmaf(v.z, w, agg[4 * q + 2]);
            agg[4 * q + 3] = fmaf(v.w, w, agg[4 * q + 3]);
        }
    }
    float t0 = 0.f, t1 = 0.f;
#pragma unroll
    for (int j = 0; j < 32; ++j) {
        float acc = sb1[j];
#pragma unroll
        for (int k = 0; k < 16; ++k) acc = fmaf(agg[k], sW1[k * 32 + j], acc);
        float h = fmaxf(acc, 0.f);
        t0 = fmaf(h, sW2[j * 2 + 0], t0);
        t1 = fmaf(h, sW2[j * 2 + 1], t1);
    }
    t[(size_t)i * 2 + 0] = t0;
    t[(size_t)i * 2 + 1] = t1;
}

// ---------------- layer 2 gather (2 feats) ----------------
__global__ void k_l2(const int* __restrict__ rowptr, const int* __restrict__ col,
                     const float* __restrict__ dinv, const float* __restrict__ t,
                     const float* __restrict__ b2, float* __restrict__ out, int n) {
    int i = blockIdx.x * blockDim.x + threadIdx.x;
    if (i >= n) return;
    float di = dinv[i];
    float2 ts = *(const float2*)(t + (size_t)i * 2);
    float acc0 = ts.x * di * di, acc1 = ts.y * di * di;
    int beg = rowptr[i], fin = rowptr[i + 1];
    for (int j = beg; j < fin; ++j) {
        int s = col[j];
        float w = dinv[s] * di;
        float2 tv = *(const float2*)(t + (size_t)s * 2);
        acc0 = fmaf(tv.x, w, acc0);
        acc1 = fmaf(tv.y, w, acc1);
    }
    out[(size_t)i * 2 + 0] = acc0 + b2[0];
    out[(size_t)i * 2 + 1] = acc1 + b2[1];
}

// ---------------- R3 CSR fallback kernels (global-atomic build) ----------------

__global__ void k_zero(int* __restrict__ cnt, int n) {
    int i = blockIdx.x * blockDim.x + threadIdx.x;
    if (i < n) cnt[i] = 0;
}
__global__ void k_hist_rank(const int* __restrict__ dst, int* __restrict__ cnt,
                            int* __restrict__ rank, int E) {
    int e = blockIdx.x * blockDim.x + threadIdx.x;
    if (e < E) rank[e] = atomicAdd(&cnt[dst[e]], 1);
}
__global__ __launch_bounds__(256) void k_blocksum(const int* __restrict__ cnt,
                                                  int* __restrict__ bsum, int n) {
    __shared__ int s[256];
    int tid = threadIdx.x;
    int bse = blockIdx.x * 1024 + tid * 4;
    int sum = 0;
#pragma unroll
    for (int q = 0; q < 4; ++q) {
        int i = bse + q;
        if (i < n) sum += cnt[i];
    }
    s[tid] = sum;
    __syncthreads();
    for (int off = 128; off > 0; off >>= 1) {
        if (tid < off) s[tid] += s[tid + off];
        __syncthreads();
    }
    if (tid == 0) bsum[blockIdx.x] = s[0];
}
__global__ __launch_bounds__(1024) void k_scan_bsums(const int* __restrict__ bsum,
                                                     int* __restrict__ boff, int nb,
                                                     int* __restrict__ rowptr, int n, int E) {
    __shared__ int s[1024];
    int tid = threadIdx.x;
    int v = (tid < nb) ? bsum[tid] : 0;
    s[tid] = v;
    __syncthreads();
    for (int off = 1; off < 1024; off <<= 1) {
        int u = (tid >= off) ? s[tid - off] : 0;
        __syncthreads();
        s[tid] += u;
        __syncthreads();
    }
    if (tid < nb) boff[tid] = s[tid] - v;
    if (tid == 0) rowptr[n] = E;
}
__global__ __launch_bounds__(256) void k_scan_apply(const int* __restrict__ cnt,
                                                    const int* __restrict__ boff,
                                                    int* __restrict__ rowptr,
                                                    float* __restrict__ dinv, int n) {
    __shared__ int s[256];
    int tid = threadIdx.x;
    int bse = blockIdx.x * 1024 + tid * 4;
    int c[4];
    int sum = 0;
#pragma unroll
    for (int q = 0; q < 4; ++q) {
        int i = bse + q;
        c[q] = (i < n) ? cnt[i] : 0;
        sum += c[q];
    }
    s[tid] = sum;
    __syncthreads();
    for (int off = 1; off < 256; off <<= 1) {
        int u = (tid >= off) ? s[tid - off] : 0;
        __syncthreads();
        s[tid] += u;
        __syncthreads();
    }
    int run = boff[blockIdx.x] + s[tid] - sum;
#pragma unroll
    for (int q = 0; q < 4; ++q) {
        int i = bse + q;
        if (i < n) {
            rowptr[i] = run;
            run += c[q];
            dinv[i] = rsqrtf((float)(c[q] + 1));
        }
    }
}
__global__ void k_fill_rank(const int* __restrict__ src, const int* __restrict__ dst,
                            const int* __restrict__ rowptr, const int* __restrict__ rank,
                            int* __restrict__ col, int E) {
    int e = blockIdx.x * blockDim.x + threadIdx.x;
    if (e >= E) return;
    int d = dst[e];
    col[rowptr[d] + rank[e]] = src[e];
}

static inline size_t align4(size_t v) { return (v + 3) & ~(size_t)3; }

extern "C" void kernel_launch(void* const* d_in, const int* in_sizes, int n_in,
                              void* d_out, int out_size, void* d_ws, size_t ws_size,
                              hipStream_t stream) {
    const float* x  = (const float*)d_in[0];
    const int*   ei = (const int*)d_in[1];
    const float* W1 = (const float*)d_in[2];
    const float* b1 = (const float*)d_in[3];
    const float* W2 = (const float*)d_in[4];
    const float* b2 = (const float*)d_in[5];
    float* out = (float*)d_out;

    const int n = in_sizes[0] / 16;
    const int E = in_sizes[1] / 2;
    const int* src = ei;
    const int* dst = ei + E;

    const int gn = (n + B - 1) / B;
    const int ge = (E + B - 1) / B;

    const int NB   = (n + BDIV - 1) / BDIV;      // dst buckets
    const int NBLK = (E + CHUNK - 1) / CHUNK;    // partition blocks

    // R5 ws layout (int units): hists[NB*NBLK] | totals[NB] | base[NB+1] |
    //   rowptr[n+1] | dinv[n] | packed[E] (t[2n] aliases after CSR build) | col[E]
    size_t o_hists  = 0;
    size_t o_totals = align4(o_hists + (size_t)NB * NBLK);
    size_t o_base   = align4(o_totals + NB);
    size_t o_rowptr = align4(o_base + NB + 1);
    size_t o_dinv   = align4(o_rowptr + n + 1);
    size_t o_packed = align4(o_dinv + n);
    size_t o_col    = align4(o_packed + E);
    size_t need_r5  = (o_col + E) * 4 + 64;

    bool r5_ok = (NB <= NB_MAX) && (NBLK <= 512) && (n <= (1 << 20)) &&
                 ((size_t)2 * n <= (size_t)E) && (ws_size >= need_r5);

    if (r5_ok) {
        int* ws = (int*)d_ws;
        int*      hists  = ws + o_hists;
        int*      totals = ws + o_totals;
        int*      base   = ws + o_base;
        int*      rowptr = ws + o_rowptr;
        float*    dinv   = (float*)(ws + o_dinv);
        unsigned* packed = (unsigned*)(ws + o_packed);
        float*    t      = (float*)packed;       // packed dead after k_bucket_csr
        int*      col    = ws + o_col;

        k_phist<<<NBLK, 256, 0, stream>>>(dst, hists, E, NB, NBLK);
        k_pscan1<<<NB, 512, 0, stream>>>(hists, totals, NBLK);
        k_pscan2<<<1, 1024, 0, stream>>>(totals, base, NB, rowptr, n, E);
        k_move<<<NBLK, 256, 0, stream>>>(src, dst, hists, base, packed, E, NB, NBLK);
        k_bucket_csr<<<NB, 256, 0, stream>>>(packed, base, rowptr, dinv, col, n);
        k_l1<<<gn, B, 0, stream>>>(x, rowptr, col, dinv, W1, b1, W2, t, n);
        k_l2<<<gn, B, 0, stream>>>(rowptr, col, dinv, t, b2, out, n);
        return;
    }

    // ---- R3 CSR fallback (global-atomic hist/fill) ----
    const int nb = (n + 1023) / 1024;
    size_t tmax = (size_t)(E > 2 * n ? E : 2 * n);
    size_t need_rank = ((size_t)(3 * n + 1 + 2 * nb) + E + tmax) * 4 + 64;
    if (ws_size >= need_rank && nb <= 1024) {
        int*   cnt    = (int*)d_ws;
        int*   rowptr = cnt + n;
        int*   col    = rowptr + (n + 1);
        float* dinv   = (float*)(col + E);
        int*   bsum   = (int*)(dinv + n);
        int*   boff   = bsum + nb;
        int*   rank   = boff + nb;
        float* t      = (float*)rank;

        k_zero<<<gn, B, 0, stream>>>(cnt, n);
        k_hist_rank<<<ge, B, 0, stream>>>(dst, cnt, rank, E);
        k_blocksum<<<nb, 256, 0, stream>>>(cnt, bsum, n);
        k_scan_bsums<<<1, 1024, 0, stream>>>(bsum, boff, nb, rowptr, n, E);
        k_scan_apply<<<nb, 256, 0, stream>>>(cnt, boff, rowptr, dinv, n);
        k_fill_rank<<<ge, B, 0, stream>>>(src, dst, rowptr, rank, col, E);
        k_l1<<<gn, B, 0, stream>>>(x, rowptr, col, dinv, W1, b1, W2, t, n);
        k_l2<<<gn, B, 0, stream>>>(rowptr, col, dinv, t, b2, out, n);
    }
}

// Round 6
// 212.590 us; speedup vs baseline: 2.1176x; 1.0070x over previous
//
#include <hip/hip_runtime.h>

// GCN 2-layer: out = A(relu(A x W1 + b1) W2) + b2, A = sym-normalized adj + self-loops.
// R6: R5's atomic-free partition CSR build + WAVE-PARALLEL gathers.
// R5's k_l1 (thread-per-node) was 92us at 13% occupancy / 3% VALUBusy: latency-bound,
// 391 blocks. k_l1w uses one wave per row (lane = feat x edge-group) -> 16x parallelism,
// coalesced 64B x-row segments, in-wave shuffle MLP. k_l2w uses 4 lanes/node.

#define B 256
#define NB_MAX 1024
#define BDIV 128          // nodes per bucket (pow2)
#define BSHIFT 7
#define CHUNK 8192        // edges per partition block

// ---------------- partition: per-block LDS histogram over buckets ----------------
__global__ __launch_bounds__(256) void k_phist(const int* __restrict__ dst,
                                               int* __restrict__ hists,
                                               int E, int NB, int NBLK) {
    __shared__ int h[NB_MAX];
    int tid = threadIdx.x, blk = blockIdx.x;
    for (int b = tid; b < NB; b += 256) h[b] = 0;
    __syncthreads();
    int start = blk * CHUNK;
    int end = min(start + CHUNK, E);
    for (int e = start + tid; e < end; e += 256)
        atomicAdd(&h[((unsigned)dst[e]) >> BSHIFT], 1);
    __syncthreads();
    for (int b = tid; b < NB; b += 256) hists[b * NBLK + blk] = h[b];
}

// per-bucket exclusive scan over NBLK block-counts (NBLK <= 512)
__global__ __launch_bounds__(512) void k_pscan1(int* __restrict__ hists,
                                                int* __restrict__ totals, int NBLK) {
    __shared__ int s[512];
    int b = blockIdx.x, tid = threadIdx.x;
    int v = (tid < NBLK) ? hists[b * NBLK + tid] : 0;
    s[tid] = v;
    __syncthreads();
    for (int off = 1; off < 512; off <<= 1) {
        int u = (tid >= off) ? s[tid - off] : 0;
        __syncthreads();
        s[tid] += u;
        __syncthreads();
    }
    if (tid < NBLK) hists[b * NBLK + tid] = s[tid] - v;  // exclusive within bucket
    if (tid == 511) totals[b] = s[511];
}

// scan bucket totals -> bucket bases (NB <= 1024); base[NB]=E; rowptr[n]=E
__global__ __launch_bounds__(1024) void k_pscan2(const int* __restrict__ totals,
                                                 int* __restrict__ base, int NB,
                                                 int* __restrict__ rowptr, int n, int E) {
    __shared__ int s[1024];
    int tid = threadIdx.x;
    int v = (tid < NB) ? totals[tid] : 0;
    s[tid] = v;
    __syncthreads();
    for (int off = 1; off < 1024; off <<= 1) {
        int u = (tid >= off) ? s[tid - off] : 0;
        __syncthreads();
        s[tid] += u;
        __syncthreads();
    }
    if (tid < NB) base[tid] = s[tid] - v;
    if (tid == 1023) { base[NB] = s[1023]; rowptr[n] = E; }
}

// move edges into bucket regions; payload = src | local_dst<<20 (no global atomics)
__global__ __launch_bounds__(256) void k_move(const int* __restrict__ src,
                                              const int* __restrict__ dst,
                                              const int* __restrict__ hists,
                                              const int* __restrict__ base,
                                              unsigned* __restrict__ packed,
                                              int E, int NB, int NBLK) {
    __shared__ int cnt[NB_MAX];
    int tid = threadIdx.x, blk = blockIdx.x;
    for (int b = tid; b < NB; b += 256) cnt[b] = base[b] + hists[b * NBLK + blk];
    __syncthreads();
    int start = blk * CHUNK;
    int end = min(start + CHUNK, E);
    for (int e = start + tid; e < end; e += 256) {
        unsigned d = (unsigned)dst[e];
        int b = d >> BSHIFT;
        int r = atomicAdd(&cnt[b], 1);
        packed[r] = (unsigned)src[e] | ((d & (BDIV - 1u)) << 20);
    }
}

// per-bucket: LDS hist over 128 local nodes -> scan -> rowptr/dinv + place col
__global__ __launch_bounds__(256) void k_bucket_csr(const unsigned* __restrict__ packed,
                                                    const int* __restrict__ base,
                                                    int* __restrict__ rowptr,
                                                    float* __restrict__ dinv,
                                                    int* __restrict__ col, int n) {
    __shared__ int lcnt[BDIV];
    __shared__ int lexc[BDIV];
    int b = blockIdx.x, tid = threadIdx.x;
    if (tid < BDIV) lcnt[tid] = 0;
    __syncthreads();
    int s0 = base[b], s1 = base[b + 1];
    for (int i = s0 + tid; i < s1; i += 256)
        atomicAdd(&lcnt[packed[i] >> 20], 1);
    __syncthreads();
    int v = (tid < BDIV) ? lcnt[tid] : 0;
    if (tid < BDIV) lexc[tid] = v;
    __syncthreads();
    for (int off = 1; off < BDIV; off <<= 1) {
        int u = (tid < BDIV && tid >= off) ? lexc[tid - off] : 0;
        __syncthreads();
        if (tid < BDIV) lexc[tid] += u;
        __syncthreads();
    }
    if (tid < BDIV) {
        lexc[tid] -= v;  // exclusive
        int node = b * BDIV + tid;
        if (node < n) {
            rowptr[node] = s0 + lexc[tid];
            dinv[node] = rsqrtf((float)(v + 1));  // +1 self-loop
        }
        lcnt[tid] = 0;  // reuse as fill cursor
    }
    __syncthreads();
    for (int i = s0 + tid; i < s1; i += 256) {
        unsigned u = packed[i];
        int l = (int)(u >> 20);
        int pos = s0 + lexc[l] + atomicAdd(&lcnt[l], 1);
        col[pos] = (int)(u & 0xFFFFFu);
    }
}

// ---------------- layer 1: WAVE-PER-ROW gather + in-wave fused MLP ----------------
// lane = (f = lane&15 feat, eg = lane>>4 edge-group). 4 edges/iter, coalesced 64B
// x-row segments. agg folded via shfl_xor(16,32); MLP: 16 shfl broadcasts + LDS W1,
// 32 lanes = hidden units, 5-round xor reduce -> t0 (lane 0) / t1 (lane 32).
__global__ __launch_bounds__(256) void k_l1w(const float* __restrict__ x,
                                             const int* __restrict__ rowptr,
                                             const int* __restrict__ col,
                                             const float* __restrict__ dinv,
                                             const float* __restrict__ W1,
                                             const float* __restrict__ b1,
                                             const float* __restrict__ W2,
                                             float* __restrict__ t, int n) {
    __shared__ float sW1[512], sW2[64], sb1[32];
    int tid = threadIdx.x;
    for (int k = tid; k < 512; k += 256) sW1[k] = W1[k];
    if (tid < 64) sW2[tid] = W2[tid];
    if (tid < 32) sb1[tid] = b1[tid];
    __syncthreads();
    int lane = tid & 63;
    int r = blockIdx.x * 4 + (tid >> 6);
    if (r >= n) return;
    int f = lane & 15, eg = lane >> 4;
    float dr = dinv[r];
    int beg = rowptr[r], fin = rowptr[r + 1];
    float acc = (eg == 0) ? x[(size_t)r * 16 + f] * dr * dr : 0.f;  // self-loop
    for (int j = beg + eg; j < fin; j += 4) {
        int s = col[j];
        acc = fmaf(x[(size_t)s * 16 + f], dinv[s] * dr, acc);
    }
    acc += __shfl_xor(acc, 16);
    acc += __shfl_xor(acc, 32);   // every lane now holds agg[f]
    int j32 = lane & 31;
    float h = sb1[j32];
#pragma unroll
    for (int k = 0; k < 16; ++k) {
        float a = __shfl(acc, k);                 // broadcast agg[k]
        h = fmaf(a, sW1[k * 32 + j32], h);
    }
    h = fmaxf(h, 0.f);
    float p = h * sW2[j32 * 2 + (lane >> 5)];     // half 0 -> t0, half 1 -> t1
#pragma unroll
    for (int off = 1; off <= 16; off <<= 1) p += __shfl_xor(p, off);
    if ((lane & 31) == 0) t[(size_t)r * 2 + (lane >> 5)] = p;
}

// ---------------- layer 2: 4 lanes per node ----------------
__global__ __launch_bounds__(256) void k_l2w(const int* __restrict__ rowptr,
                                             const int* __restrict__ col,
                                             const float* __restrict__ dinv,
                                             const float* __restrict__ t,
                                             const float* __restrict__ b2,
                                             float* __restrict__ out, int n) {
    int g = blockIdx.x * 256 + threadIdx.x;
    int i = g >> 2, q = g & 3;
    if (i >= n) return;
    float di = dinv[i];
    int beg = rowptr[i], fin = rowptr[i + 1];
    float a0 = 0.f, a1 = 0.f;
    if (q == 0) {
        float2 ts = *(const float2*)(t + (size_t)i * 2);
        a0 = ts.x * di * di; a1 = ts.y * di * di;   // self-loop
    }
    for (int j = beg + q; j < fin; j += 4) {
        int s = col[j];
        float w = dinv[s] * di;
        float2 tv = *(const float2*)(t + (size_t)s * 2);
        a0 = fmaf(tv.x, w, a0);
        a1 = fmaf(tv.y, w, a1);
    }
    a0 += __shfl_xor(a0, 1); a0 += __shfl_xor(a0, 2);
    a1 += __shfl_xor(a1, 1); a1 += __shfl_xor(a1, 2);
    if (q == 0) {
        out[(size_t)i * 2 + 0] = a0 + b2[0];
        out[(size_t)i * 2 + 1] = a1 + b2[1];
    }
}

// ---------------- R3 CSR fallback kernels (global-atomic build) ----------------

__global__ void k_zero(int* __restrict__ cnt, int n) {
    int i = blockIdx.x * blockDim.x + threadIdx.x;
    if (i < n) cnt[i] = 0;
}
__global__ void k_hist_rank(const int* __restrict__ dst, int* __restrict__ cnt,
                            int* __restrict__ rank, int E) {
    int e = blockIdx.x * blockDim.x + threadIdx.x;
    if (e < E) rank[e] = atomicAdd(&cnt[dst[e]], 1);
}
__global__ __launch_bounds__(256) void k_blocksum(const int* __restrict__ cnt,
                                                  int* __restrict__ bsum, int n) {
    __shared__ int s[256];
    int tid = threadIdx.x;
    int bse = blockIdx.x * 1024 + tid * 4;
    int sum = 0;
#pragma unroll
    for (int q = 0; q < 4; ++q) {
        int i = bse + q;
        if (i < n) sum += cnt[i];
    }
    s[tid] = sum;
    __syncthreads();
    for (int off = 128; off > 0; off >>= 1) {
        if (tid < off) s[tid] += s[tid + off];
        __syncthreads();
    }
    if (tid == 0) bsum[blockIdx.x] = s[0];
}
__global__ __launch_bounds__(1024) void k_scan_bsums(const int* __restrict__ bsum,
                                                     int* __restrict__ boff, int nb,
                                                     int* __restrict__ rowptr, int n, int E) {
    __shared__ int s[1024];
    int tid = threadIdx.x;
    int v = (tid < nb) ? bsum[tid] : 0;
    s[tid] = v;
    __syncthreads();
    for (int off = 1; off < 1024; off <<= 1) {
        int u = (tid >= off) ? s[tid - off] : 0;
        __syncthreads();
        s[tid] += u;
        __syncthreads();
    }
    if (tid < nb) boff[tid] = s[tid] - v;
    if (tid == 0) rowptr[n] = E;
}
__global__ __launch_bounds__(256) void k_scan_apply(const int* __restrict__ cnt,
                                                    const int* __restrict__ boff,
                                                    int* __restrict__ rowptr,
                                                    float* __restrict__ dinv, int n) {
    __shared__ int s[256];
    int tid = threadIdx.x;
    int bse = blockIdx.x * 1024 + tid * 4;
    int c[4];
    int sum = 0;
#pragma unroll
    for (int q = 0; q < 4; ++q) {
        int i = bse + q;
        c[q] = (i < n) ? cnt[i] : 0;
        sum += c[q];
    }
    s[tid] = sum;
    __syncthreads();
    for (int off = 1; off < 256; off <<= 1) {
        int u = (tid >= off) ? s[tid - off] : 0;
        __syncthreads();
        s[tid] += u;
        __syncthreads();
    }
    int run = boff[blockIdx.x] + s[tid] - sum;
#pragma unroll
    for (int q = 0; q < 4; ++q) {
        int i = bse + q;
        if (i < n) {
            rowptr[i] = run;
            run += c[q];
            dinv[i] = rsqrtf((float)(c[q] + 1));
        }
    }
}
__global__ void k_fill_rank(const int* __restrict__ src, const int* __restrict__ dst,
                            const int* __restrict__ rowptr, const int* __restrict__ rank,
                            int* __restrict__ col, int E) {
    int e = blockIdx.x * blockDim.x + threadIdx.x;
    if (e >= E) return;
    int d = dst[e];
    col[rowptr[d] + rank[e]] = src[e];
}

static inline size_t align4(size_t v) { return (v + 3) & ~(size_t)3; }

extern "C" void kernel_launch(void* const* d_in, const int* in_sizes, int n_in,
                              void* d_out, int out_size, void* d_ws, size_t ws_size,
                              hipStream_t stream) {
    const float* x  = (const float*)d_in[0];
    const int*   ei = (const int*)d_in[1];
    const float* W1 = (const float*)d_in[2];
    const float* b1 = (const float*)d_in[3];
    const float* W2 = (const float*)d_in[4];
    const float* b2 = (const float*)d_in[5];
    float* out = (float*)d_out;

    const int n = in_sizes[0] / 16;
    const int E = in_sizes[1] / 2;
    const int* src = ei;
    const int* dst = ei + E;

    const int gn = (n + B - 1) / B;
    const int ge = (E + B - 1) / B;

    const int NB   = (n + BDIV - 1) / BDIV;      // dst buckets
    const int NBLK = (E + CHUNK - 1) / CHUNK;    // partition blocks

    // ws layout (int units): hists[NB*NBLK] | totals[NB] | base[NB+1] |
    //   rowptr[n+1] | dinv[n] | packed[E] (t[2n] aliases after CSR build) | col[E]
    size_t o_hists  = 0;
    size_t o_totals = align4(o_hists + (size_t)NB * NBLK);
    size_t o_base   = align4(o_totals + NB);
    size_t o_rowptr = align4(o_base + NB + 1);
    size_t o_dinv   = align4(o_rowptr + n + 1);
    size_t o_packed = align4(o_dinv + n);
    size_t o_col    = align4(o_packed + E);
    size_t need_r5  = (o_col + E) * 4 + 64;

    bool r5_ok = (NB <= NB_MAX) && (NBLK <= 512) && (n <= (1 << 20)) &&
                 ((size_t)2 * n <= (size_t)E) && (ws_size >= need_r5);

    if (r5_ok) {
        int* ws = (int*)d_ws;
        int*      hists  = ws + o_hists;
        int*      totals = ws + o_totals;
        int*      base   = ws + o_base;
        int*      rowptr = ws + o_rowptr;
        float*    dinv   = (float*)(ws + o_dinv);
        unsigned* packed = (unsigned*)(ws + o_packed);
        float*    t      = (float*)packed;       // packed dead after k_bucket_csr
        int*      col    = ws + o_col;

        k_phist<<<NBLK, 256, 0, stream>>>(dst, hists, E, NB, NBLK);
        k_pscan1<<<NB, 512, 0, stream>>>(hists, totals, NBLK);
        k_pscan2<<<1, 1024, 0, stream>>>(totals, base, NB, rowptr, n, E);
        k_move<<<NBLK, 256, 0, stream>>>(src, dst, hists, base, packed, E, NB, NBLK);
        k_bucket_csr<<<NB, 256, 0, stream>>>(packed, base, rowptr, dinv, col, n);
        k_l1w<<<(n + 3) / 4, 256, 0, stream>>>(x, rowptr, col, dinv, W1, b1, W2, t, n);
        k_l2w<<<(4 * n + 255) / 256, 256, 0, stream>>>(rowptr, col, dinv, t, b2, out, n);
        return;
    }

    // ---- R3 CSR fallback (global-atomic hist/fill) ----
    const int nb = (n + 1023) / 1024;
    size_t tmax = (size_t)(E > 2 * n ? E : 2 * n);
    size_t need_rank = ((size_t)(3 * n + 1 + 2 * nb) + E + tmax) * 4 + 64;
    if (ws_size >= need_rank && nb <= 1024) {
        int*   cnt    = (int*)d_ws;
        int*   rowptr = cnt + n;
        int*   col    = rowptr + (n + 1);
        float* dinv   = (float*)(col + E);
        int*   bsum   = (int*)(dinv + n);
        int*   boff   = bsum + nb;
        int*   rank   = boff + nb;
        float* t      = (float*)rank;

        k_zero<<<gn, B, 0, stream>>>(cnt, n);
        k_hist_rank<<<ge, B, 0, stream>>>(dst, cnt, rank, E);
        k_blocksum<<<nb, 256, 0, stream>>>(cnt, bsum, n);
        k_scan_bsums<<<1, 1024, 0, stream>>>(bsum, boff, nb, rowptr, n, E);
        k_scan_apply<<<nb, 256, 0, stream>>>(cnt, boff, rowptr, dinv, n);
        k_fill_rank<<<ge, B, 0, stream>>>(src, dst, rowptr, rank, col, E);
        k_l1w<<<(n + 3) / 4, 256, 0, stream>>>(x, rowptr, col, dinv, W1, b1, W2, t, n);
        k_l2w<<<(4 * n + 255) / 256, 256, 0, stream>>>(rowptr, col, dinv, t, b2, out, n);
    }
}

// Round 7
// 167.180 us; speedup vs baseline: 2.6928x; 1.2716x over previous
//
#include <hip/hip_runtime.h>
#include <hip/hip_fp16.h>

// GCN 2-layer: out = A(relu(A x W1 + b1) W2) + b2, A = sym-normalized adj + self-loops.
// R7: R6's FETCH counters showed k_l1w thrashing L2 (x f32 = 6.4MB > 4MB/XCD L2 ->
// 108MB HBM fetch @ 1TB/s). Fix: gather fp16 pre-scaled x16 = fp16(x*dinv) (3.2MB,
// L2-resident), 8 edges in flight per wave, dinv factored out of inner loops; t stored
// pre-scaled by dinv_r so layer-2's loop is also pure add. x16/t alias dead `packed`.

#define B 256
#define NB_MAX 1024
#define BDIV 128          // nodes per bucket (pow2)
#define BSHIFT 7
#define CHUNK 8192        // edges per partition block

// ---------------- partition: per-block LDS histogram over buckets ----------------
__global__ __launch_bounds__(256) void k_phist(const int* __restrict__ dst,
                                               int* __restrict__ hists,
                                               int E, int NB, int NBLK) {
    __shared__ int h[NB_MAX];
    int tid = threadIdx.x, blk = blockIdx.x;
    for (int b = tid; b < NB; b += 256) h[b] = 0;
    __syncthreads();
    int start = blk * CHUNK;
    int end = min(start + CHUNK, E);
    for (int e = start + tid; e < end; e += 256)
        atomicAdd(&h[((unsigned)dst[e]) >> BSHIFT], 1);
    __syncthreads();
    for (int b = tid; b < NB; b += 256) hists[b * NBLK + blk] = h[b];
}

// per-bucket exclusive scan over NBLK block-counts (NBLK <= 512)
__global__ __launch_bounds__(512) void k_pscan1(int* __restrict__ hists,
                                                int* __restrict__ totals, int NBLK) {
    __shared__ int s[512];
    int b = blockIdx.x, tid = threadIdx.x;
    int v = (tid < NBLK) ? hists[b * NBLK + tid] : 0;
    s[tid] = v;
    __syncthreads();
    for (int off = 1; off < 512; off <<= 1) {
        int u = (tid >= off) ? s[tid - off] : 0;
        __syncthreads();
        s[tid] += u;
        __syncthreads();
    }
    if (tid < NBLK) hists[b * NBLK + tid] = s[tid] - v;  // exclusive within bucket
    if (tid == 511) totals[b] = s[511];
}

// scan bucket totals -> bucket bases (NB <= 1024); base[NB]=E; rowptr[n]=E
__global__ __launch_bounds__(1024) void k_pscan2(const int* __restrict__ totals,
                                                 int* __restrict__ base, int NB,
                                                 int* __restrict__ rowptr, int n, int E) {
    __shared__ int s[1024];
    int tid = threadIdx.x;
    int v = (tid < NB) ? totals[tid] : 0;
    s[tid] = v;
    __syncthreads();
    for (int off = 1; off < 1024; off <<= 1) {
        int u = (tid >= off) ? s[tid - off] : 0;
        __syncthreads();
        s[tid] += u;
        __syncthreads();
    }
    if (tid < NB) base[tid] = s[tid] - v;
    if (tid == 1023) { base[NB] = s[1023]; rowptr[n] = E; }
}

// move edges into bucket regions; payload = src | local_dst<<20 (no global atomics)
__global__ __launch_bounds__(256) void k_move(const int* __restrict__ src,
                                              const int* __restrict__ dst,
                                              const int* __restrict__ hists,
                                              const int* __restrict__ base,
                                              unsigned* __restrict__ packed,
                                              int E, int NB, int NBLK) {
    __shared__ int cnt[NB_MAX];
    int tid = threadIdx.x, blk = blockIdx.x;
    for (int b = tid; b < NB; b += 256) cnt[b] = base[b] + hists[b * NBLK + blk];
    __syncthreads();
    int start = blk * CHUNK;
    int end = min(start + CHUNK, E);
    for (int e = start + tid; e < end; e += 256) {
        unsigned d = (unsigned)dst[e];
        int b = d >> BSHIFT;
        int r = atomicAdd(&cnt[b], 1);
        packed[r] = (unsigned)src[e] | ((d & (BDIV - 1u)) << 20);
    }
}

// per-bucket: LDS hist over 128 local nodes -> scan -> rowptr/dinv + place col
__global__ __launch_bounds__(256) void k_bucket_csr(const unsigned* __restrict__ packed,
                                                    const int* __restrict__ base,
                                                    int* __restrict__ rowptr,
                                                    float* __restrict__ dinv,
                                                    int* __restrict__ col, int n) {
    __shared__ int lcnt[BDIV];
    __shared__ int lexc[BDIV];
    int b = blockIdx.x, tid = threadIdx.x;
    if (tid < BDIV) lcnt[tid] = 0;
    __syncthreads();
    int s0 = base[b], s1 = base[b + 1];
    for (int i = s0 + tid; i < s1; i += 256)
        atomicAdd(&lcnt[packed[i] >> 20], 1);
    __syncthreads();
    int v = (tid < BDIV) ? lcnt[tid] : 0;
    if (tid < BDIV) lexc[tid] = v;
    __syncthreads();
    for (int off = 1; off < BDIV; off <<= 1) {
        int u = (tid < BDIV && tid >= off) ? lexc[tid - off] : 0;
        __syncthreads();
        if (tid < BDIV) lexc[tid] += u;
        __syncthreads();
    }
    if (tid < BDIV) {
        lexc[tid] -= v;  // exclusive
        int node = b * BDIV + tid;
        if (node < n) {
            rowptr[node] = s0 + lexc[tid];
            dinv[node] = rsqrtf((float)(v + 1));  // +1 self-loop
        }
        lcnt[tid] = 0;  // reuse as fill cursor
    }
    __syncthreads();
    for (int i = s0 + tid; i < s1; i += 256) {
        unsigned u = packed[i];
        int l = (int)(u >> 20);
        int pos = s0 + lexc[l] + atomicAdd(&lcnt[l], 1);
        col[pos] = (int)(u & 0xFFFFFu);
    }
}

// ---------------- x16 = fp16(x * dinv): L2-resident gather operand ----------------
__global__ void k_prep(const float* __restrict__ x, const float* __restrict__ dinv,
                       __half2* __restrict__ x16, int n8) {
    int g = blockIdx.x * blockDim.x + threadIdx.x;  // one half2 (2 feats)
    if (g >= n8) return;
    float d = dinv[g >> 3];
    float2 v = ((const float2*)x)[g];
    x16[g] = __float22half2_rn(make_float2(v.x * d, v.y * d));
}

// ---------------- layer 1: wave-per-row fp16 gather + in-wave fused MLP ----------
// lane = (h = lane&7 feat-pair, eg = lane>>3 edge-group): 8 edges in flight, 4B/lane.
// Inner loop is pure load+add (dinv factored out). Fold shfl_xor(8,16,32); MLP via
// 16 shfl broadcasts + LDS W1; t stored pre-scaled by dinv_r for layer 2.
__global__ __launch_bounds__(256) void k_l1w(const __half2* __restrict__ x16,
                                             const int* __restrict__ rowptr,
                                             const int* __restrict__ col,
                                             const float* __restrict__ dinv,
                                             const float* __restrict__ W1,
                                             const float* __restrict__ b1,
                                             const float* __restrict__ W2,
                                             float* __restrict__ t, int n) {
    __shared__ float sW1[512], sW2[64], sb1[32];
    int tid = threadIdx.x;
    for (int k = tid; k < 512; k += 256) sW1[k] = W1[k];
    if (tid < 64) sW2[tid] = W2[tid];
    if (tid < 32) sb1[tid] = b1[tid];
    __syncthreads();
    int lane = tid & 63;
    int r = blockIdx.x * 4 + (tid >> 6);
    if (r >= n) return;
    int h = lane & 7, eg = lane >> 3;
    float dr = dinv[r];
    int beg = rowptr[r], fin = rowptr[r + 1];
    float s0 = 0.f, s1 = 0.f;
    if (eg == 0) {  // self-loop: x16[r] = x*dinv_r, *dr later -> x*dinv_r^2
        float2 f = __half22float2(x16[(size_t)r * 8 + h]);
        s0 = f.x; s1 = f.y;
    }
    for (int j = beg + eg; j < fin; j += 8) {
        int s = col[j];
        float2 f = __half22float2(x16[(size_t)s * 8 + h]);
        s0 += f.x; s1 += f.y;
    }
    s0 += __shfl_xor(s0, 8);  s1 += __shfl_xor(s1, 8);
    s0 += __shfl_xor(s0, 16); s1 += __shfl_xor(s1, 16);
    s0 += __shfl_xor(s0, 32); s1 += __shfl_xor(s1, 32);
    s0 *= dr; s1 *= dr;  // agg[2h], agg[2h+1] in every lane
    int j32 = lane & 31;
    float hv = sb1[j32];
#pragma unroll
    for (int k = 0; k < 16; ++k) {
        float a = __shfl((k & 1) ? s1 : s0, k >> 1);
        hv = fmaf(a, sW1[k * 32 + j32], hv);
    }
    hv = fmaxf(hv, 0.f);
    float p = hv * sW2[j32 * 2 + (lane >> 5)];  // lanes<32 -> t0, lanes>=32 -> t1
#pragma unroll
    for (int off = 1; off <= 16; off <<= 1) p += __shfl_xor(p, off);
    if ((lane & 31) == 0) t[(size_t)r * 2 + (lane >> 5)] = p * dr;  // pre-scaled
}

// ---------------- layer 2: 8 lanes per node, pure-add loop ----------------
__global__ __launch_bounds__(256) void k_l2w(const int* __restrict__ rowptr,
                                             const int* __restrict__ col,
                                             const float* __restrict__ dinv,
                                             const float* __restrict__ ts,
                                             const float* __restrict__ b2,
                                             float* __restrict__ out, int n) {
    int g = blockIdx.x * 256 + threadIdx.x;
    int i = g >> 3, q = g & 7;
    if (i >= n) return;
    float di = dinv[i];
    int beg = rowptr[i], fin = rowptr[i + 1];
    float a0 = 0.f, a1 = 0.f;
    if (q == 0) {  // self: ts[i] = t*dinv_i; *di at end -> t*dinv_i^2
        float2 tv = *(const float2*)(ts + (size_t)i * 2);
        a0 = tv.x; a1 = tv.y;
    }
    for (int j = beg + q; j < fin; j += 8) {
        int s = col[j];
        float2 tv = *(const float2*)(ts + (size_t)s * 2);
        a0 += tv.x; a1 += tv.y;
    }
    a0 += __shfl_xor(a0, 1); a1 += __shfl_xor(a1, 1);
    a0 += __shfl_xor(a0, 2); a1 += __shfl_xor(a1, 2);
    a0 += __shfl_xor(a0, 4); a1 += __shfl_xor(a1, 4);
    if (q == 0) {
        out[(size_t)i * 2 + 0] = fmaf(a0, di, b2[0]);
        out[(size_t)i * 2 + 1] = fmaf(a1, di, b2[1]);
    }
}

// ---------------- R3 CSR fallback kernels (global-atomic build) ----------------

__global__ void k_zero(int* __restrict__ cnt, int n) {
    int i = blockIdx.x * blockDim.x + threadIdx.x;
    if (i < n) cnt[i] = 0;
}
__global__ void k_hist_rank(const int* __restrict__ dst, int* __restrict__ cnt,
                            int* __restrict__ rank, int E) {
    int e = blockIdx.x * blockDim.x + threadIdx.x;
    if (e < E) rank[e] = atomicAdd(&cnt[dst[e]], 1);
}
__global__ __launch_bounds__(256) void k_blocksum(const int* __restrict__ cnt,
                                                  int* __restrict__ bsum, int n) {
    __shared__ int s[256];
    int tid = threadIdx.x;
    int bse = blockIdx.x * 1024 + tid * 4;
    int sum = 0;
#pragma unroll
    for (int q = 0; q < 4; ++q) {
        int i = bse + q;
        if (i < n) sum += cnt[i];
    }
    s[tid] = sum;
    __syncthreads();
    for (int off = 128; off > 0; off >>= 1) {
        if (tid < off) s[tid] += s[tid + off];
        __syncthreads();
    }
    if (tid == 0) bsum[blockIdx.x] = s[0];
}
__global__ __launch_bounds__(1024) void k_scan_bsums(const int* __restrict__ bsum,
                                                     int* __restrict__ boff, int nb,
                                                     int* __restrict__ rowptr, int n, int E) {
    __shared__ int s[1024];
    int tid = threadIdx.x;
    int v = (tid < nb) ? bsum[tid] : 0;
    s[tid] = v;
    __syncthreads();
    for (int off = 1; off < 1024; off <<= 1) {
        int u = (tid >= off) ? s[tid - off] : 0;
        __syncthreads();
        s[tid] += u;
        __syncthreads();
    }
    if (tid < nb) boff[tid] = s[tid] - v;
    if (tid == 0) rowptr[n] = E;
}
__global__ __launch_bounds__(256) void k_scan_apply(const int* __restrict__ cnt,
                                                    const int* __restrict__ boff,
                                                    int* __restrict__ rowptr,
                                                    float* __restrict__ dinv, int n) {
    __shared__ int s[256];
    int tid = threadIdx.x;
    int bse = blockIdx.x * 1024 + tid * 4;
    int c[4];
    int sum = 0;
#pragma unroll
    for (int q = 0; q < 4; ++q) {
        int i = bse + q;
        c[q] = (i < n) ? cnt[i] : 0;
        sum += c[q];
    }
    s[tid] = sum;
    __syncthreads();
    for (int off = 1; off < 256; off <<= 1) {
        int u = (tid >= off) ? s[tid - off] : 0;
        __syncthreads();
        s[tid] += u;
        __syncthreads();
    }
    int run = boff[blockIdx.x] + s[tid] - sum;
#pragma unroll
    for (int q = 0; q < 4; ++q) {
        int i = bse + q;
        if (i < n) {
            rowptr[i] = run;
            run += c[q];
            dinv[i] = rsqrtf((float)(c[q] + 1));
        }
    }
}
__global__ void k_fill_rank(const int* __restrict__ src, const int* __restrict__ dst,
                            const int* __restrict__ rowptr, const int* __restrict__ rank,
                            int* __restrict__ col, int E) {
    int e = blockIdx.x * blockDim.x + threadIdx.x;
    if (e >= E) return;
    int d = dst[e];
    col[rowptr[d] + rank[e]] = src[e];
}

static inline size_t align4(size_t v) { return (v + 3) & ~(size_t)3; }

extern "C" void kernel_launch(void* const* d_in, const int* in_sizes, int n_in,
                              void* d_out, int out_size, void* d_ws, size_t ws_size,
                              hipStream_t stream) {
    const float* x  = (const float*)d_in[0];
    const int*   ei = (const int*)d_in[1];
    const float* W1 = (const float*)d_in[2];
    const float* b1 = (const float*)d_in[3];
    const float* W2 = (const float*)d_in[4];
    const float* b2 = (const float*)d_in[5];
    float* out = (float*)d_out;

    const int n = in_sizes[0] / 16;
    const int E = in_sizes[1] / 2;
    const int* src = ei;
    const int* dst = ei + E;

    const int gn = (n + B - 1) / B;
    const int ge = (E + B - 1) / B;
    const int n8 = n * 8;

    const int NB   = (n + BDIV - 1) / BDIV;      // dst buckets
    const int NBLK = (E + CHUNK - 1) / CHUNK;    // partition blocks

    // ws layout (int units): hists[NB*NBLK] | totals[NB] | base[NB+1] |
    //   rowptr[n+1] | dinv[n] | packed[E] | col[E]
    // after k_bucket_csr, packed region is reused: t[2n] at +0, x16[8n] at +2n
    size_t o_hists  = 0;
    size_t o_totals = align4(o_hists + (size_t)NB * NBLK);
    size_t o_base   = align4(o_totals + NB);
    size_t o_rowptr = align4(o_base + NB + 1);
    size_t o_dinv   = align4(o_rowptr + n + 1);
    size_t o_packed = align4(o_dinv + n);
    size_t o_col    = align4(o_packed + E);
    size_t need_r5  = (o_col + E) * 4 + 64;

    bool r5_ok = (NB <= NB_MAX) && (NBLK <= 512) && (n <= (1 << 20)) &&
                 ((size_t)10 * n <= (size_t)E) && (ws_size >= need_r5);

    if (r5_ok) {
        int* ws = (int*)d_ws;
        int*      hists  = ws + o_hists;
        int*      totals = ws + o_totals;
        int*      base   = ws + o_base;
        int*      rowptr = ws + o_rowptr;
        float*    dinv   = (float*)(ws + o_dinv);
        unsigned* packed = (unsigned*)(ws + o_packed);
        int*      col    = ws + o_col;
        float*    t      = (float*)packed;                 // packed dead after CSR build
        __half2*  x16    = (__half2*)(packed + 2 * n);     // 10n ints <= E ints

        k_phist<<<NBLK, 256, 0, stream>>>(dst, hists, E, NB, NBLK);
        k_pscan1<<<NB, 512, 0, stream>>>(hists, totals, NBLK);
        k_pscan2<<<1, 1024, 0, stream>>>(totals, base, NB, rowptr, n, E);
        k_move<<<NBLK, 256, 0, stream>>>(src, dst, hists, base, packed, E, NB, NBLK);
        k_bucket_csr<<<NB, 256, 0, stream>>>(packed, base, rowptr, dinv, col, n);
        k_prep<<<(n8 + 255) / 256, 256, 0, stream>>>(x, dinv, x16, n8);
        k_l1w<<<(n + 3) / 4, 256, 0, stream>>>(x16, rowptr, col, dinv, W1, b1, W2, t, n);
        k_l2w<<<(8 * n + 255) / 256, 256, 0, stream>>>(rowptr, col, dinv, t, b2, out, n);
        return;
    }

    // ---- R3 CSR fallback (global-atomic hist/fill) ----
    const int nb = (n + 1023) / 1024;
    size_t rmax = (size_t)E > (size_t)10 * n ? (size_t)E : (size_t)10 * n;
    size_t need_rank = ((size_t)(3 * n + 1 + 2 * nb) + E + rmax) * 4 + 64;
    if (ws_size >= need_rank && nb <= 1024) {
        int*   cnt    = (int*)d_ws;
        int*   rowptr = cnt + n;
        int*   col    = rowptr + (n + 1);
        float* dinv   = (float*)(col + E);
        int*   bsum   = (int*)(dinv + n);
        int*   boff   = bsum + nb;
        int*   rank   = boff + nb;                 // dead after k_fill_rank
        float* t      = (float*)rank;
        __half2* x16  = (__half2*)(rank + 2 * n);

        k_zero<<<gn, B, 0, stream>>>(cnt, n);
        k_hist_rank<<<ge, B, 0, stream>>>(dst, cnt, rank, E);
        k_blocksum<<<nb, 256, 0, stream>>>(cnt, bsum, n);
        k_scan_bsums<<<1, 1024, 0, stream>>>(bsum, boff, nb, rowptr, n, E);
        k_scan_apply<<<nb, 256, 0, stream>>>(cnt, boff, rowptr, dinv, n);
        k_fill_rank<<<ge, B, 0, stream>>>(src, dst, rowptr, rank, col, E);
        k_prep<<<(n8 + 255) / 256, 256, 0, stream>>>(x, dinv, x16, n8);
        k_l1w<<<(n + 3) / 4, 256, 0, stream>>>(x16, rowptr, col, dinv, W1, b1, W2, t, n);
        k_l2w<<<(8 * n + 255) / 256, 256, 0, stream>>>(rowptr, col, dinv, t, b2, out, n);
    }
}

// Round 8
// 154.764 us; speedup vs baseline: 2.9089x; 1.0802x over previous
//
#include <hip/hip_runtime.h>
#include <hip/hip_fp16.h>

// GCN 2-layer: out = A(relu(A x W1 + b1) W2) + b2, A = sym-normalized adj + self-loops.
// R8: R7 counters showed k_l1w latency-bound (VALUBusy 33%, occ 74%, FETCH already
// L2-resident): dependent col->x16 chain. Fix: dual-stream software pipeline (4 loads
// in flight/lane). k_move's 3.2M isolated 4B scattered stores (one ~32B fabric granule
// each) are staged: in-LDS bucket sort per 8K chunk -> coalesced run writes.

#define B 256
#define NB_MAX 1024
#define BDIV 128          // nodes per bucket (pow2)
#define BSHIFT 7
#define CHUNK 8192        // edges per partition block

// ---------------- partition: per-block LDS histogram over buckets ----------------
__global__ __launch_bounds__(256) void k_phist(const int* __restrict__ dst,
                                               int* __restrict__ hists,
                                               int E, int NB, int NBLK) {
    __shared__ int h[NB_MAX];
    int tid = threadIdx.x, blk = blockIdx.x;
    for (int b = tid; b < NB; b += 256) h[b] = 0;
    __syncthreads();
    int start = blk * CHUNK;
    int end = min(start + CHUNK, E);
    for (int e = start + tid; e < end; e += 256)
        atomicAdd(&h[((unsigned)dst[e]) >> BSHIFT], 1);
    __syncthreads();
    for (int b = tid; b < NB; b += 256) hists[b * NBLK + blk] = h[b];
}

// per-bucket exclusive scan over NBLK block-counts (NBLK <= 512)
__global__ __launch_bounds__(512) void k_pscan1(int* __restrict__ hists,
                                                int* __restrict__ totals, int NBLK) {
    __shared__ int s[512];
    int b = blockIdx.x, tid = threadIdx.x;
    int v = (tid < NBLK) ? hists[b * NBLK + tid] : 0;
    s[tid] = v;
    __syncthreads();
    for (int off = 1; off < 512; off <<= 1) {
        int u = (tid >= off) ? s[tid - off] : 0;
        __syncthreads();
        s[tid] += u;
        __syncthreads();
    }
    if (tid < NBLK) hists[b * NBLK + tid] = s[tid] - v;  // exclusive within bucket
    if (tid == 511) totals[b] = s[511];
}

// scan bucket totals -> bucket bases (NB <= 1024); base[NB]=E; rowptr[n]=E
__global__ __launch_bounds__(1024) void k_pscan2(const int* __restrict__ totals,
                                                 int* __restrict__ base, int NB,
                                                 int* __restrict__ rowptr, int n, int E) {
    __shared__ int s[1024];
    int tid = threadIdx.x;
    int v = (tid < NB) ? totals[tid] : 0;
    s[tid] = v;
    __syncthreads();
    for (int off = 1; off < 1024; off <<= 1) {
        int u = (tid >= off) ? s[tid - off] : 0;
        __syncthreads();
        s[tid] += u;
        __syncthreads();
    }
    if (tid < NB) base[tid] = s[tid] - v;
    if (tid == 1023) { base[NB] = s[1023]; rowptr[n] = E; }
}

// move edges into bucket regions, LDS-staged for coalesced writes.
// payload = src | local_dst<<20. Bucket sidecar (u16) recovers write base.
__global__ __launch_bounds__(256) void k_move(const int* __restrict__ src,
                                              const int* __restrict__ dst,
                                              const int* __restrict__ hists,
                                              const int* __restrict__ base,
                                              unsigned* __restrict__ packed,
                                              int E, int NB, int NBLK) {
    __shared__ unsigned stage[CHUNK];            // 32 KB
    __shared__ unsigned short stage_b[CHUNK];    // 16 KB
    __shared__ int lh[NB_MAX];                   // hist -> cursor
    __shared__ int lexc[NB_MAX];                 // exclusive offsets
    __shared__ int gb[NB_MAX];                   // global write base per bucket
    __shared__ int part[256];
    int tid = threadIdx.x, blk = blockIdx.x;
    int start = blk * CHUNK;
    int end = min(start + CHUNK, E);
    for (int b = tid; b < NB; b += 256) lh[b] = 0;
    __syncthreads();
    // 1. local hist
    for (int e = start + tid; e < end; e += 256)
        atomicAdd(&lh[((unsigned)dst[e]) >> BSHIFT], 1);
    __syncthreads();
    // 2. exclusive scan lh -> lexc (thread handles 4 entries)
    int t4 = tid * 4;
    int a0 = 0, a1 = 0, a2 = 0, a3 = 0;
    if (t4 + 0 < NB) a0 = lh[t4 + 0];
    if (t4 + 1 < NB) a1 = lh[t4 + 1];
    if (t4 + 2 < NB) a2 = lh[t4 + 2];
    if (t4 + 3 < NB) a3 = lh[t4 + 3];
    int sum = a0 + a1 + a2 + a3;
    part[tid] = sum;
    __syncthreads();
    for (int off = 1; off < 256; off <<= 1) {
        int u = (tid >= off) ? part[tid - off] : 0;
        __syncthreads();
        part[tid] += u;
        __syncthreads();
    }
    int run = part[tid] - sum;
    if (t4 + 0 < NB) { lexc[t4 + 0] = run; run += a0; }
    if (t4 + 1 < NB) { lexc[t4 + 1] = run; run += a1; }
    if (t4 + 2 < NB) { lexc[t4 + 2] = run; run += a2; }
    if (t4 + 3 < NB) { lexc[t4 + 3] = run; run += a3; }
    __syncthreads();
    // 3. cursor init + global base
    for (int b = tid; b < NB; b += 256) {
        lh[b] = lexc[b];
        gb[b] = base[b] + hists[b * NBLK + blk] - lexc[b];
    }
    __syncthreads();
    // 4. place into LDS stage (bucket-sorted)
    for (int e = start + tid; e < end; e += 256) {
        unsigned d = (unsigned)dst[e];
        int b = d >> BSHIFT;
        int r = atomicAdd(&lh[b], 1);
        stage[r] = (unsigned)src[e] | ((d & (BDIV - 1u)) << 20);
        stage_b[r] = (unsigned short)b;
    }
    __syncthreads();
    // 5. linear write-out: consecutive i in a bucket run -> consecutive global addr
    int cnt = end - start;
    for (int i = tid; i < cnt; i += 256)
        packed[gb[stage_b[i]] + i] = stage[i];
}

// per-bucket: LDS hist over 128 local nodes -> scan -> rowptr/dinv + place col
__global__ __launch_bounds__(256) void k_bucket_csr(const unsigned* __restrict__ packed,
                                                    const int* __restrict__ base,
                                                    int* __restrict__ rowptr,
                                                    float* __restrict__ dinv,
                                                    int* __restrict__ col, int n) {
    __shared__ int lcnt[BDIV];
    __shared__ int lexc[BDIV];
    int b = blockIdx.x, tid = threadIdx.x;
    if (tid < BDIV) lcnt[tid] = 0;
    __syncthreads();
    int s0 = base[b], s1 = base[b + 1];
    for (int i = s0 + tid; i < s1; i += 256)
        atomicAdd(&lcnt[packed[i] >> 20], 1);
    __syncthreads();
    int v = (tid < BDIV) ? lcnt[tid] : 0;
    if (tid < BDIV) lexc[tid] = v;
    __syncthreads();
    for (int off = 1; off < BDIV; off <<= 1) {
        int u = (tid < BDIV && tid >= off) ? lexc[tid - off] : 0;
        __syncthreads();
        if (tid < BDIV) lexc[tid] += u;
        __syncthreads();
    }
    if (tid < BDIV) {
        lexc[tid] -= v;  // exclusive
        int node = b * BDIV + tid;
        if (node < n) {
            rowptr[node] = s0 + lexc[tid];
            dinv[node] = rsqrtf((float)(v + 1));  // +1 self-loop
        }
        lcnt[tid] = 0;  // reuse as fill cursor
    }
    __syncthreads();
    for (int i = s0 + tid; i < s1; i += 256) {
        unsigned u = packed[i];
        int l = (int)(u >> 20);
        int pos = s0 + lexc[l] + atomicAdd(&lcnt[l], 1);
        col[pos] = (int)(u & 0xFFFFFu);
    }
}

// ---------------- x16 = fp16(x * dinv): L2-resident gather operand ----------------
__global__ void k_prep(const float* __restrict__ x, const float* __restrict__ dinv,
                       __half2* __restrict__ x16, int n8) {
    int g = blockIdx.x * blockDim.x + threadIdx.x;  // one half2 (2 feats)
    if (g >= n8) return;
    float d = dinv[g >> 3];
    float2 v = ((const float2*)x)[g];
    x16[g] = __float22half2_rn(make_float2(v.x * d, v.y * d));
}

// ---------------- layer 1: wave-per-row fp16 gather + in-wave fused MLP ----------
// lane = (h = lane&7 feat-pair, eg = lane>>3 edge-group). Dual-stream software
// pipeline: two independent chains (j, j+8; stride 16) + col prefetch -> 4 loads in
// flight per lane. Inner loop pure load+add (dinv factored out).
__global__ __launch_bounds__(256) void k_l1w(const __half2* __restrict__ x16,
                                             const int* __restrict__ rowptr,
                                             const int* __restrict__ col,
                                             const float* __restrict__ dinv,
                                             const float* __restrict__ W1,
                                             const float* __restrict__ b1,
                                             const float* __restrict__ W2,
                                             float* __restrict__ t, int n) {
    __shared__ float sW1[512], sW2[64], sb1[32];
    int tid = threadIdx.x;
    for (int k = tid; k < 512; k += 256) sW1[k] = W1[k];
    if (tid < 64) sW2[tid] = W2[tid];
    if (tid < 32) sb1[tid] = b1[tid];
    __syncthreads();
    int lane = tid & 63;
    int r = blockIdx.x * 4 + (tid >> 6);
    if (r >= n) return;
    int h = lane & 7, eg = lane >> 3;
    float dr = dinv[r];
    int beg = rowptr[r], fin = rowptr[r + 1];
    float s0 = 0.f, s1 = 0.f;
    if (eg == 0) {  // self-loop: x16[r] = x*dinv_r, *dr later -> x*dinv_r^2
        float2 f = __half22float2(x16[(size_t)r * 8 + h]);
        s0 = f.x; s1 = f.y;
    }
    int jA = beg + eg, jB = jA + 8;
    int sA = (jA < fin) ? col[jA] : -1;
    int sB = (jB < fin) ? col[jB] : -1;
    while (sA >= 0) {
        // issue both gathers, then prefetch next col pair before consuming
        float2 fA = __half22float2(x16[(size_t)sA * 8 + h]);
        float2 fB = make_float2(0.f, 0.f);
        if (sB >= 0) fB = __half22float2(x16[(size_t)sB * 8 + h]);
        jA += 16; jB += 16;
        sA = (jA < fin) ? col[jA] : -1;
        sB = (jB < fin) ? col[jB] : -1;
        s0 += fA.x + fB.x;
        s1 += fA.y + fB.y;
    }
    s0 += __shfl_xor(s0, 8);  s1 += __shfl_xor(s1, 8);
    s0 += __shfl_xor(s0, 16); s1 += __shfl_xor(s1, 16);
    s0 += __shfl_xor(s0, 32); s1 += __shfl_xor(s1, 32);
    s0 *= dr; s1 *= dr;  // agg[2h], agg[2h+1] in every lane
    int j32 = lane & 31;
    float hv = sb1[j32];
#pragma unroll
    for (int k = 0; k < 16; ++k) {
        float a = __shfl((k & 1) ? s1 : s0, k >> 1);
        hv = fmaf(a, sW1[k * 32 + j32], hv);
    }
    hv = fmaxf(hv, 0.f);
    float p = hv * sW2[j32 * 2 + (lane >> 5)];  // lanes<32 -> t0, lanes>=32 -> t1
#pragma unroll
    for (int off = 1; off <= 16; off <<= 1) p += __shfl_xor(p, off);
    if ((lane & 31) == 0) t[(size_t)r * 2 + (lane >> 5)] = p * dr;  // pre-scaled
}

// ---------------- layer 2: 8 lanes per node, dual-stream pure-add loop ----------
__global__ __launch_bounds__(256) void k_l2w(const int* __restrict__ rowptr,
                                             const int* __restrict__ col,
                                             const float* __restrict__ dinv,
                                             const float* __restrict__ ts,
                                             const float* __restrict__ b2,
                                             float* __restrict__ out, int n) {
    int g = blockIdx.x * 256 + threadIdx.x;
    int i = g >> 3, q = g & 7;
    if (i >= n) return;
    float di = dinv[i];
    int beg = rowptr[i], fin = rowptr[i + 1];
    float a0 = 0.f, a1 = 0.f;
    if (q == 0) {  // self: ts[i] = t*dinv_i; *di at end -> t*dinv_i^2
        float2 tv = *(const float2*)(ts + (size_t)i * 2);
        a0 = tv.x; a1 = tv.y;
    }
    int jA = beg + q, jB = jA + 8;
    int sA = (jA < fin) ? col[jA] : -1;
    int sB = (jB < fin) ? col[jB] : -1;
    while (sA >= 0) {
        float2 tA = *(const float2*)(ts + (size_t)sA * 2);
        float2 tB = make_float2(0.f, 0.f);
        if (sB >= 0) tB = *(const float2*)(ts + (size_t)sB * 2);
        jA += 16; jB += 16;
        sA = (jA < fin) ? col[jA] : -1;
        sB = (jB < fin) ? col[jB] : -1;
        a0 += tA.x + tB.x;
        a1 += tA.y + tB.y;
    }
    a0 += __shfl_xor(a0, 1); a1 += __shfl_xor(a1, 1);
    a0 += __shfl_xor(a0, 2); a1 += __shfl_xor(a1, 2);
    a0 += __shfl_xor(a0, 4); a1 += __shfl_xor(a1, 4);
    if (q == 0) {
        out[(size_t)i * 2 + 0] = fmaf(a0, di, b2[0]);
        out[(size_t)i * 2 + 1] = fmaf(a1, di, b2[1]);
    }
}

// ---------------- R3 CSR fallback kernels (global-atomic build) ----------------

__global__ void k_zero(int* __restrict__ cnt, int n) {
    int i = blockIdx.x * blockDim.x + threadIdx.x;
    if (i < n) cnt[i] = 0;
}
__global__ void k_hist_rank(const int* __restrict__ dst, int* __restrict__ cnt,
                            int* __restrict__ rank, int E) {
    int e = blockIdx.x * blockDim.x + threadIdx.x;
    if (e < E) rank[e] = atomicAdd(&cnt[dst[e]], 1);
}
__global__ __launch_bounds__(256) void k_blocksum(const int* __restrict__ cnt,
                                                  int* __restrict__ bsum, int n) {
    __shared__ int s[256];
    int tid = threadIdx.x;
    int bse = blockIdx.x * 1024 + tid * 4;
    int sum = 0;
#pragma unroll
    for (int q = 0; q < 4; ++q) {
        int i = bse + q;
        if (i < n) sum += cnt[i];
    }
    s[tid] = sum;
    __syncthreads();
    for (int off = 128; off > 0; off >>= 1) {
        if (tid < off) s[tid] += s[tid + off];
        __syncthreads();
    }
    if (tid == 0) bsum[blockIdx.x] = s[0];
}
__global__ __launch_bounds__(1024) void k_scan_bsums(const int* __restrict__ bsum,
                                                     int* __restrict__ boff, int nb,
                                                     int* __restrict__ rowptr, int n, int E) {
    __shared__ int s[1024];
    int tid = threadIdx.x;
    int v = (tid < nb) ? bsum[tid] : 0;
    s[tid] = v;
    __syncthreads();
    for (int off = 1; off < 1024; off <<= 1) {
        int u = (tid >= off) ? s[tid - off] : 0;
        __syncthreads();
        s[tid] += u;
        __syncthreads();
    }
    if (tid < nb) boff[tid] = s[tid] - v;
    if (tid == 0) rowptr[n] = E;
}
__global__ __launch_bounds__(256) void k_scan_apply(const int* __restrict__ cnt,
                                                    const int* __restrict__ boff,
                                                    int* __restrict__ rowptr,
                                                    float* __restrict__ dinv, int n) {
    __shared__ int s[256];
    int tid = threadIdx.x;
    int bse = blockIdx.x * 1024 + tid * 4;
    int c[4];
    int sum = 0;
#pragma unroll
    for (int q = 0; q < 4; ++q) {
        int i = bse + q;
        c[q] = (i < n) ? cnt[i] : 0;
        sum += c[q];
    }
    s[tid] = sum;
    __syncthreads();
    for (int off = 1; off < 256; off <<= 1) {
        int u = (tid >= off) ? s[tid - off] : 0;
        __syncthreads();
        s[tid] += u;
        __syncthreads();
    }
    int run = boff[blockIdx.x] + s[tid] - sum;
#pragma unroll
    for (int q = 0; q < 4; ++q) {
        int i = bse + q;
        if (i < n) {
            rowptr[i] = run;
            run += c[q];
            dinv[i] = rsqrtf((float)(c[q] + 1));
        }
    }
}
__global__ void k_fill_rank(const int* __restrict__ src, const int* __restrict__ dst,
                            const int* __restrict__ rowptr, const int* __restrict__ rank,
                            int* __restrict__ col, int E) {
    int e = blockIdx.x * blockDim.x + threadIdx.x;
    if (e >= E) return;
    int d = dst[e];
    col[rowptr[d] + rank[e]] = src[e];
}

static inline size_t align4(size_t v) { return (v + 3) & ~(size_t)3; }

extern "C" void kernel_launch(void* const* d_in, const int* in_sizes, int n_in,
                              void* d_out, int out_size, void* d_ws, size_t ws_size,
                              hipStream_t stream) {
    const float* x  = (const float*)d_in[0];
    const int*   ei = (const int*)d_in[1];
    const float* W1 = (const float*)d_in[2];
    const float* b1 = (const float*)d_in[3];
    const float* W2 = (const float*)d_in[4];
    const float* b2 = (const float*)d_in[5];
    float* out = (float*)d_out;

    const int n = in_sizes[0] / 16;
    const int E = in_sizes[1] / 2;
    const int* src = ei;
    const int* dst = ei + E;

    const int gn = (n + B - 1) / B;
    const int ge = (E + B - 1) / B;
    const int n8 = n * 8;

    const int NB   = (n + BDIV - 1) / BDIV;      // dst buckets
    const int NBLK = (E + CHUNK - 1) / CHUNK;    // partition blocks

    // ws layout (int units): hists[NB*NBLK] | totals[NB] | base[NB+1] |
    //   rowptr[n+1] | dinv[n] | packed[E] | col[E]
    // after k_bucket_csr, packed region reused: t[2n] at +0, x16[8n] at +2n
    size_t o_hists  = 0;
    size_t o_totals = align4(o_hists + (size_t)NB * NBLK);
    size_t o_base   = align4(o_totals + NB);
    size_t o_rowptr = align4(o_base + NB + 1);
    size_t o_dinv   = align4(o_rowptr + n + 1);
    size_t o_packed = align4(o_dinv + n);
    size_t o_col    = align4(o_packed + E);
    size_t need_r5  = (o_col + E) * 4 + 64;

    bool r5_ok = (NB <= NB_MAX) && (NBLK <= 512) && (n <= (1 << 20)) &&
                 ((size_t)10 * n <= (size_t)E) && (ws_size >= need_r5);

    if (r5_ok) {
        int* ws = (int*)d_ws;
        int*      hists  = ws + o_hists;
        int*      totals = ws + o_totals;
        int*      base   = ws + o_base;
        int*      rowptr = ws + o_rowptr;
        float*    dinv   = (float*)(ws + o_dinv);
        unsigned* packed = (unsigned*)(ws + o_packed);
        int*      col    = ws + o_col;
        float*    t      = (float*)packed;                 // packed dead after CSR build
        __half2*  x16    = (__half2*)(packed + 2 * n);     // 10n ints <= E ints

        k_phist<<<NBLK, 256, 0, stream>>>(dst, hists, E, NB, NBLK);
        k_pscan1<<<NB, 512, 0, stream>>>(hists, totals, NBLK);
        k_pscan2<<<1, 1024, 0, stream>>>(totals, base, NB, rowptr, n, E);
        k_move<<<NBLK, 256, 0, stream>>>(src, dst, hists, base, packed, E, NB, NBLK);
        k_bucket_csr<<<NB, 256, 0, stream>>>(packed, base, rowptr, dinv, col, n);
        k_prep<<<(n8 + 255) / 256, 256, 0, stream>>>(x, dinv, x16, n8);
        k_l1w<<<(n + 3) / 4, 256, 0, stream>>>(x16, rowptr, col, dinv, W1, b1, W2, t, n);
        k_l2w<<<(8 * n + 255) / 256, 256, 0, stream>>>(rowptr, col, dinv, t, b2, out, n);
        return;
    }

    // ---- R3 CSR fallback (global-atomic hist/fill) ----
    const int nb = (n + 1023) / 1024;
    size_t rmax = (size_t)E > (size_t)10 * n ? (size_t)E : (size_t)10 * n;
    size_t need_rank = ((size_t)(3 * n + 1 + 2 * nb) + E + rmax) * 4 + 64;
    if (ws_size >= need_rank && nb <= 1024) {
        int*   cnt    = (int*)d_ws;
        int*   rowptr = cnt + n;
        int*   col    = rowptr + (n + 1);
        float* dinv   = (float*)(col + E);
        int*   bsum   = (int*)(dinv + n);
        int*   boff   = bsum + nb;
        int*   rank   = boff + nb;                 // dead after k_fill_rank
        float* t      = (float*)rank;
        __half2* x16  = (__half2*)(rank + 2 * n);

        k_zero<<<gn, B, 0, stream>>>(cnt, n);
        k_hist_rank<<<ge, B, 0, stream>>>(dst, cnt, rank, E);
        k_blocksum<<<nb, 256, 0, stream>>>(cnt, bsum, n);
        k_scan_bsums<<<1, 1024, 0, stream>>>(bsum, boff, nb, rowptr, n, E);
        k_scan_apply<<<nb, 256, 0, stream>>>(cnt, boff, rowptr, dinv, n);
        k_fill_rank<<<ge, B, 0, stream>>>(src, dst, rowptr, rank, col, E);
        k_prep<<<(n8 + 255) / 256, 256, 0, stream>>>(x, dinv, x16, n8);
        k_l1w<<<(n + 3) / 4, 256, 0, stream>>>(x16, rowptr, col, dinv, W1, b1, W2, t, n);
        k_l2w<<<(8 * n + 255) / 256, 256, 0, stream>>>(rowptr, col, dinv, t, b2, out, n);
    }
}